// Round 5
// baseline (141.578 us; speedup 1.0000x reference)
//
#include <hip/hip_runtime.h>

#define KN 1000000
#define NCOLS 70400
#define NPAIRS (KN / 32)          // 2 tiles (32 elems) per wave-iteration
#define NBLK 1024
#define NTHR 256
#define NREP 16                   // >= #XCDs(8); slots 8..15 unused safety margin

typedef _Float16 f16x8 __attribute__((ext_vector_type(8)));
typedef float    f32x4 __attribute__((ext_vector_type(4)));

__device__ __forceinline__ unsigned encodeF(float f) {
    unsigned b = __float_as_uint(f);
    return (b & 0x80000000u) ? ~b : (b | 0x80000000u);
}
__device__ __forceinline__ float decodeF(unsigned e) {
    unsigned b = (e & 0x80000000u) ? (e & 0x7fffffffu) : ~e;
    return __uint_as_float(b);
}
#define ENC_SENT 0x34E76980u   // encodeF(-9999999.0f)

#define MFMA16(a, b, c) __builtin_amdgcn_mfma_f32_16x16x32_f16((a), (b), (c), 0, 0, 0)

// LDS layout of raw fp32 weights (staged coalesced once per block):
#define OW1 0
#define OB1 72
#define OW2 90
#define OB2 738
#define OW3 774
#define OB3 2070
#define OW4 2106
#define OB4 2142
#define NWTS 2143

// R11 history: R1 = 56us main kernel, MfmaUtil 7%, VALUBusy 28%, WRITE=43.5MB
// = 44B x 1M atomics -> every device-scope atomicMax bypasses L2 (per-XCD L2s
// non-coherent -> agent scope must go memory-side) and same-line RMW chains
// serialize: 4400 lines x ~227 atomics x ~250ns ~= 56us. Matches.
// R2 (read-before-atomic) FAILED: cached reads of atomically-hot lines
// ping-pong at the coherence point (FETCH 18->380MB, dur 230us).
// R3/R4 (d_ws replication) NEVER ENGAGED: ws_size < 563KB (counters
// byte-identical to R1) -> harness provides no usable workspace.
// R5: static __device__ replica table (module-load allocation, graph-safe).
//  (a) replica selected by the REAL XCD id (s_getreg HW_REG_XCC_ID, 0-7 on
//      MI355X) -> same-line chains split 8x, no dispatch-order assumption.
//  (b) workgroup-scope atomicMax: replica j is touched only by XCD j, whose
//      CUs share one L2 = the atomic execution point when the L2-bypass is
//      dropped -> atomics run in-L2, write-back (~20ns same-line) instead of
//      write-through memory-side (~250ns). End-of-dispatch L2 writeback
//      publishes replicas to the decode kernel.

__device__ unsigned g_rep[NREP * NCOLS];   // 4.5 MB static accumulator replicas

__global__ __launch_bounds__(NTHR)
__attribute__((amdgpu_waves_per_eu(4, 4)))
void mlp_scatter_mfma(const float* __restrict__ x, const int* __restrict__ tidx,
                      const float* __restrict__ W1, const float* __restrict__ b1,
                      const float* __restrict__ W2, const float* __restrict__ b2,
                      const float* __restrict__ W3, const float* __restrict__ b3,
                      const float* __restrict__ W4, const float* __restrict__ b4)
{
    __shared__ float    sw[NWTS];           // raw fp32 weights, block-shared
    __shared__ _Float16 smem[4][2][1152];   // 4 waves x 2 tiles x (16*72) halfs

    const int t    = threadIdx.x;
    const int lane = t & 63;
    const int wv   = t >> 6;
    const int quad = lane >> 4;
    const int n    = lane & 15;

    // ---- coalesced one-time stage of all weights into LDS ----
    for (int i = t; i < 72;   i += NTHR) sw[OW1 + i] = W1[i];
    for (int i = t; i < 18;   i += NTHR) sw[OB1 + i] = b1[i];
    for (int i = t; i < 648;  i += NTHR) sw[OW2 + i] = W2[i];
    for (int i = t; i < 36;   i += NTHR) sw[OB2 + i] = b2[i];
    for (int i = t; i < 1296; i += NTHR) sw[OW3 + i] = W3[i];
    for (int i = t; i < 36;   i += NTHR) sw[OB3 + i] = b3[i];
    for (int i = t; i < 36;   i += NTHR) sw[OW4 + i] = W4[i];
    if (t == 0) sw[OB4] = b4[0];

    _Float16* Ha = &smem[wv][0][0];
    _Float16* Hb = &smem[wv][1][0];

    // one-time zero of cols 48..63 (all 16 rows) in both tile buffers
    for (int i = lane; i < 128; i += 64) {
        const int row = i >> 3, dc = i & 7;
        ((unsigned*)(Ha + row * 72 + 48))[dc] = 0u;
        ((unsigned*)(Hb + row * 72 + 48))[dc] = 0u;
    }
    __syncthreads();

    // ---- weight B-fragments, built once per wave from LDS (no TA cost) ----
    auto bf = [&](int off, int OUT, int IN, int tt, int ks) {
        f16x8 r;
#pragma unroll
        for (int j = 0; j < 8; ++j) {
            int k  = ks * 32 + quad * 8 + j;
            int ng = tt * 16 + n;
            float w = (ng < OUT && k < IN) ? sw[off + ng * IN + k] : 0.0f;
            r[j] = (_Float16)w;
        }
        return r;
    };
    const f16x8 B1_0 = bf(OW1, 18,  4, 0, 0), B1_1 = bf(OW1, 18,  4, 1, 0);
    const f16x8 B2_0 = bf(OW2, 36, 18, 0, 0), B2_1 = bf(OW2, 36, 18, 1, 0), B2_2 = bf(OW2, 36, 18, 2, 0);
    const f16x8 B3_00 = bf(OW3, 36, 36, 0, 0), B3_01 = bf(OW3, 36, 36, 0, 1);
    const f16x8 B3_10 = bf(OW3, 36, 36, 1, 0), B3_11 = bf(OW3, 36, 36, 1, 1);
    const f16x8 B3_20 = bf(OW3, 36, 36, 2, 0), B3_21 = bf(OW3, 36, 36, 2, 1);

    const float bias1_0 = sw[OB1 + n];
    const float bias1_1 = (n < 2) ? sw[OB1 + 16 + n] : 0.0f;
    const float bias2_0 = sw[OB2 + n], bias2_1 = sw[OB2 + 16 + n];
    const float bias2_2 = (n < 4) ? sw[OB2 + 32 + n] : 0.0f;
    const float bias3_0 = sw[OB3 + n], bias3_1 = sw[OB3 + 16 + n];
    const float bias3_2 = (n < 4) ? sw[OB3 + 32 + n] : 0.0f;
    const float b4s = sw[OB4];
    const float w4_0 = sw[OW4 + n], w4_1 = sw[OW4 + 16 + n];
    const float w4_2 = (n < 4) ? sw[OW4 + 32 + n] : 0.0f;

    // ---- replica owned by this block's PHYSICAL XCD (no dispatch-order
    //      assumption: we read the hardware register) ----
    unsigned xcc;
    asm volatile("s_getreg_b32 %0, hwreg(HW_REG_XCC_ID)" : "=s"(xcc));
    unsigned* __restrict__ dst = g_rep + (size_t)(xcc & (NREP - 1)) * NCOLS;

    const int gw = (blockIdx.x * blockDim.x + t) >> 6;
    const int nw = (gridDim.x * blockDim.x) >> 6;

    // ---- prefetch-rotate state for pair p ----
    float cxa0, cxa1, cxa2, cxa3, cxb0, cxb1, cxb2, cxb3;
    int cca = 0, ccb = 0;
    if (gw < NPAIRS) {
        const int kb = gw * 32;
        cxa0 = x[0 * KN + kb + n];      cxb0 = x[0 * KN + kb + 16 + n];
        cxa1 = x[1 * KN + kb + n];      cxb1 = x[1 * KN + kb + 16 + n];
        cxa2 = x[2 * KN + kb + n];      cxb2 = x[2 * KN + kb + 16 + n];
        cxa3 = x[3 * KN + kb + n];      cxb3 = x[3 * KN + kb + 16 + n];
        cca  = tidx[2 * (kb + n) + 1];  ccb  = tidx[2 * (kb + 16 + n) + 1];
    }

    for (int p = gw; p < NPAIRS; ) {
        const int pn = p + nw;
        const float xa0 = cxa0, xa1 = cxa1, xa2 = cxa2, xa3 = cxa3;
        const float xb0 = cxb0, xb1 = cxb1, xb2 = cxb2, xb3 = cxb3;
        const int cola = cca, colb = ccb;
        if (pn < NPAIRS) {
            const int kb = pn * 32;
            cxa0 = x[0 * KN + kb + n];      cxb0 = x[0 * KN + kb + 16 + n];
            cxa1 = x[1 * KN + kb + n];      cxb1 = x[1 * KN + kb + 16 + n];
            cxa2 = x[2 * KN + kb + n];      cxb2 = x[2 * KN + kb + 16 + n];
            cxa3 = x[3 * KN + kb + n];      cxb3 = x[3 * KN + kb + 16 + n];
            cca  = tidx[2 * (kb + n) + 1];  ccb  = tidx[2 * (kb + 16 + n) + 1];
        }

        // ---- L1: A-frags direct from x (real k<4, quad 0 only) ----
        f16x8 a1a = {}, a1b = {};
        if (quad == 0) {
            a1a[0] = (_Float16)xa0; a1a[1] = (_Float16)xa1;
            a1a[2] = (_Float16)xa2; a1a[3] = (_Float16)xa3;
            a1b[0] = (_Float16)xb0; a1b[1] = (_Float16)xb1;
            a1b[2] = (_Float16)xb2; a1b[3] = (_Float16)xb3;
        }
        f32x4 c0a = {bias1_0, bias1_0, bias1_0, bias1_0};
        f32x4 c1a = {bias1_1, bias1_1, bias1_1, bias1_1};
        f32x4 c0b = c0a, c1b = c1a;
        c0a = MFMA16(a1a, B1_0, c0a);  c0b = MFMA16(a1b, B1_0, c0b);
        c1a = MFMA16(a1a, B1_1, c1a);  c1b = MFMA16(a1b, B1_1, c1b);
#pragma unroll
        for (int r = 0; r < 4; ++r) {
            const int row = (quad * 4 + r) * 72;
            Ha[row + n]      = (_Float16)fmaxf(c0a[r], 0.0f);
            Ha[row + 16 + n] = (_Float16)fmaxf(c1a[r], 0.0f);
            Hb[row + n]      = (_Float16)fmaxf(c0b[r], 0.0f);
            Hb[row + 16 + n] = (_Float16)fmaxf(c1b[r], 0.0f);
        }

        // ---- L2: read A (k 0..31), 3 MFMA per tile, overwrite cols 0..47 ----
        const f16x8 a2a = *(const f16x8*)&Ha[n * 72 + quad * 8];
        const f16x8 a2b = *(const f16x8*)&Hb[n * 72 + quad * 8];
        f32x4 d0a = {bias2_0, bias2_0, bias2_0, bias2_0};
        f32x4 d1a = {bias2_1, bias2_1, bias2_1, bias2_1};
        f32x4 d2a = {bias2_2, bias2_2, bias2_2, bias2_2};
        f32x4 d0b = d0a, d1b = d1a, d2b = d2a;
        d0a = MFMA16(a2a, B2_0, d0a);  d0b = MFMA16(a2b, B2_0, d0b);
        d1a = MFMA16(a2a, B2_1, d1a);  d1b = MFMA16(a2b, B2_1, d1b);
        d2a = MFMA16(a2a, B2_2, d2a);  d2b = MFMA16(a2b, B2_2, d2b);
#pragma unroll
        for (int r = 0; r < 4; ++r) {
            const int row = (quad * 4 + r) * 72;
            Ha[row + n]      = (_Float16)fmaxf(d0a[r], 0.0f);
            Ha[row + 16 + n] = (_Float16)fmaxf(d1a[r], 0.0f);
            Ha[row + 32 + n] = (_Float16)fmaxf(d2a[r], 0.0f);
            Hb[row + n]      = (_Float16)fmaxf(d0b[r], 0.0f);
            Hb[row + 16 + n] = (_Float16)fmaxf(d1b[r], 0.0f);
            Hb[row + 32 + n] = (_Float16)fmaxf(d2b[r], 0.0f);
        }

        // ---- L3: 6 MFMA per tile (k real 36; k>=36 B-weights are zero) ----
        const f16x8 a30a = *(const f16x8*)&Ha[n * 72 + quad * 8];
        const f16x8 a31a = *(const f16x8*)&Ha[n * 72 + 32 + quad * 8];
        const f16x8 a30b = *(const f16x8*)&Hb[n * 72 + quad * 8];
        const f16x8 a31b = *(const f16x8*)&Hb[n * 72 + 32 + quad * 8];
        f32x4 e0a = {bias3_0, bias3_0, bias3_0, bias3_0};
        f32x4 e1a = {bias3_1, bias3_1, bias3_1, bias3_1};
        f32x4 e2a = {bias3_2, bias3_2, bias3_2, bias3_2};
        f32x4 e0b = e0a, e1b = e1a, e2b = e2a;
        e0a = MFMA16(a30a, B3_00, e0a);  e0a = MFMA16(a31a, B3_01, e0a);
        e1a = MFMA16(a30a, B3_10, e1a);  e1a = MFMA16(a31a, B3_11, e1a);
        e2a = MFMA16(a30a, B3_20, e2a);  e2a = MFMA16(a31a, B3_21, e2a);
        e0b = MFMA16(a30b, B3_00, e0b);  e0b = MFMA16(a31b, B3_01, e0b);
        e1b = MFMA16(a30b, B3_10, e1b);  e1b = MFMA16(a31b, B3_11, e1b);
        e2b = MFMA16(a30b, B3_20, e2b);  e2b = MFMA16(a31b, B3_21, e2b);

        // ---- L4 in VALU: v[elem] = sum_out W4[out]*relu(h3[elem][out]) ----
        float pa[4], pb[4];
#pragma unroll
        for (int r = 0; r < 4; ++r) {
            pa[r] = fmaf(w4_0, fmaxf(e0a[r], 0.0f),
                    fmaf(w4_1, fmaxf(e1a[r], 0.0f),
                         w4_2 * fmaxf(e2a[r], 0.0f)));
            pb[r] = fmaf(w4_0, fmaxf(e0b[r], 0.0f),
                    fmaf(w4_1, fmaxf(e1b[r], 0.0f),
                         w4_2 * fmaxf(e2b[r], 0.0f)));
        }
#pragma unroll
        for (int m = 8; m >= 1; m >>= 1) {
#pragma unroll
            for (int r = 0; r < 4; ++r) {
                pa[r] += __shfl_xor(pa[r], m, 16);
                pb[r] += __shfl_xor(pb[r], m, 16);
            }
        }
        if ((n >> 2) == quad) {
            const int r = n & 3;
            const unsigned ea = encodeF(pa[r] + b4s) - ENC_SENT;
            const unsigned eb = encodeF(pb[r] + b4s) - ENC_SENT;
            // XCD-private replica -> workgroup scope keeps the atomic in this
            // XCD's L2 (shared by all its CUs), write-back not write-through
            __hip_atomic_fetch_max(&dst[cola], ea, __ATOMIC_RELAXED,
                                   __HIP_MEMORY_SCOPE_WORKGROUP);
            __hip_atomic_fetch_max(&dst[colb], eb, __ATOMIC_RELAXED,
                                   __HIP_MEMORY_SCOPE_WORKGROUP);
        }

        p = pn;
    }
}

__global__ __launch_bounds__(256) void init_kernel() {
    int gid = blockIdx.x * blockDim.x + threadIdx.x;
    if (gid < NREP * NCOLS) g_rep[gid] = 0u;   // == encode(SENTINEL) - bias
}

__global__ __launch_bounds__(256) void decode_kernel(float* __restrict__ out,
                                                     int out_size) {
    int gid = blockIdx.x * blockDim.x + threadIdx.x;
    if (gid < out_size) {
        float r = 1.0f;
        if (gid < NCOLS) {
            unsigned m = g_rep[gid];
#pragma unroll
            for (int i = 1; i < NREP; ++i) {
                unsigned v = g_rep[i * NCOLS + gid];
                m = (v > m) ? v : m;
            }
            r = decodeF(m + ENC_SENT);
        }
        out[gid] = r;
    }
}

extern "C" void kernel_launch(void* const* d_in, const int* in_sizes, int n_in,
                              void* d_out, int out_size, void* d_ws, size_t ws_size,
                              hipStream_t stream) {
    const float* x    = (const float*)d_in[0];   // (1,4,1,K)
    const int*   tidx = (const int*)d_in[1];     // (K,2)
    const float* W1 = (const float*)d_in[2];
    const float* b1 = (const float*)d_in[3];
    const float* W2 = (const float*)d_in[4];
    const float* b2 = (const float*)d_in[5];
    const float* W3 = (const float*)d_in[6];
    const float* b3 = (const float*)d_in[7];
    const float* W4 = (const float*)d_in[8];
    const float* b4 = (const float*)d_in[9];

    init_kernel<<<(NREP * NCOLS + 255) / 256, 256, 0, stream>>>();

    mlp_scatter_mfma<<<NBLK, NTHR, 0, stream>>>(
        x, tidx, W1, b1, W2, b2, W3, b3, W4, b4);

    decode_kernel<<<(out_size + 255) / 256, 256, 0, stream>>>(
        (float*)d_out, out_size);
}

// Round 7
// 136.034 us; speedup vs baseline: 1.0408x; 1.0408x over previous
//
#include <hip/hip_runtime.h>

#define KN 1000000
#define NCOLS 70400
#define NPAIRS (KN / 32)          // 2 elem-tiles (32 elems) per wave-iteration
#define NBLK 1024
#define NTHR 256

typedef _Float16 f16x4 __attribute__((ext_vector_type(4)));
typedef float    f32x4 __attribute__((ext_vector_type(4)));

// 16x16x16 f16 MFMA: A[m][k] m=lane&15, k=quad*4+j; B[k][n] n=lane&15,
// k=quad*4+j; D[m][n] n=lane&15, m=quad*4+r.  KEY: A, B, D share the same
// per-lane structure, so with orientation D[feature][elem], relu(D) of layer
// L is DIRECTLY the B-operand of layer L+1 -> no LDS transpose between
// layers at all.  (R6 build fix: the K=16 legacy intrinsic is spelled
// ...16x16x16f16, NOT ...16x16x16_f16 — compiler note confirmed.)
#define MFMA16(a, b, c) __builtin_amdgcn_mfma_f32_16x16x16f16((a), (b), (c), 0, 0, 0)

__device__ __forceinline__ unsigned encodeF(float f) {
    unsigned b = __float_as_uint(f);
    return (b & 0x80000000u) ? ~b : (b | 0x80000000u);
}
__device__ __forceinline__ float decodeF(unsigned e) {
    unsigned b = (e & 0x80000000u) ? (e & 0x7fffffffu) : ~e;
    return __uint_as_float(b);
}
#define ENC_SENT 0x34E76980u   // encodeF(-9999999.0f)

// LDS layout of raw fp32 weights (staged coalesced once per block; used only
// in the pre-loop fragment build -> loop itself is 100% LDS-free):
#define OW1 0
#define OB1 72
#define OW2 90
#define OB2 738
#define OW3 774
#define OB3 2070
#define OW4 2106
#define OB4 2142
#define NWTS 2143

// R11 history: R1 = 56us main, MfmaUtil 7%, VALUBusy 28%, WRITE=43.5MB.
// R2 (read-filter) FAILED: cached reads of atomic-hot lines ping-pong
// (FETCH 380MB). R3/R4 (ws replication) never engaged (no workspace).
// R5 (8x XCD-private replicas + workgroup-scope atomics): ZERO delta ->
// same-line atomic contention theory FALSIFIED. Budget says the invariant
// 56us is LDS-pipe + layer-transpose latency: ~490 LDS cyc/iter (~25us/CU)
// + serial MFMA->LDS->sync->LDS->MFMA chains at only ~11 waves/CU.
// R6/R7: eliminate ALL loop LDS via [feature][elem] orientation + 16x16x16
// MFMA (D of layer L == B-operand of layer L+1, bit-compatible). Weights
// live as A-fragments in VGPRs. Shuffles 32->4/iter. Atomics identical
// to R1 (single d_out table, device scope) - single variable changed.

__global__ __launch_bounds__(NTHR)
void mlp_scatter_mfma(const float* __restrict__ x, const int* __restrict__ tidx,
                      const float* __restrict__ W1, const float* __restrict__ b1,
                      const float* __restrict__ W2, const float* __restrict__ b2,
                      const float* __restrict__ W3, const float* __restrict__ b3,
                      const float* __restrict__ W4, const float* __restrict__ b4,
                      unsigned* __restrict__ outU)
{
    __shared__ float sw[NWTS];          // raw fp32 weights (pre-loop use only)

    const int t    = threadIdx.x;
    const int lane = t & 63;
    const int quad = lane >> 4;
    const int n    = lane & 15;

    // ---- coalesced one-time stage of all weights into LDS ----
    for (int i = t; i < 72;   i += NTHR) sw[OW1 + i] = W1[i];
    for (int i = t; i < 18;   i += NTHR) sw[OB1 + i] = b1[i];
    for (int i = t; i < 648;  i += NTHR) sw[OW2 + i] = W2[i];
    for (int i = t; i < 36;   i += NTHR) sw[OB2 + i] = b2[i];
    for (int i = t; i < 1296; i += NTHR) sw[OW3 + i] = W3[i];
    for (int i = t; i < 36;   i += NTHR) sw[OB3 + i] = b3[i];
    for (int i = t; i < 36;   i += NTHR) sw[OW4 + i] = W4[i];
    if (t == 0) sw[OB4] = b4[0];
    __syncthreads();

    // ---- A-fragments of W (OUT x IN): tile tt (m = tt*16 + n), k-slice s
    //      (k = s*16 + quad*4 + j), zero-padded outside real dims ----
    auto af = [&](int off, int OUT, int IN, int tt, int s) {
        f16x4 r;
#pragma unroll
        for (int j = 0; j < 4; ++j) {
            const int m = tt * 16 + n;
            const int k = s * 16 + quad * 4 + j;
            const float w = (m < OUT && k < IN) ? sw[off + m * IN + k] : 0.0f;
            r[j] = (_Float16)w;
        }
        return r;
    };
    // ---- per-lane f32x4 of a length-OUT vector at rows tt*16+quad*4+r ----
    auto bv = [&](int off, int OUT, int tt) {
        f32x4 c;
#pragma unroll
        for (int r = 0; r < 4; ++r) {
            const int m = tt * 16 + quad * 4 + r;
            c[r] = (m < OUT) ? sw[off + m] : 0.0f;
        }
        return c;
    };

    const f16x4 A1_0  = af(OW1, 18,  4, 0, 0), A1_1  = af(OW1, 18,  4, 1, 0);
    const f16x4 A2_00 = af(OW2, 36, 18, 0, 0), A2_01 = af(OW2, 36, 18, 0, 1);
    const f16x4 A2_10 = af(OW2, 36, 18, 1, 0), A2_11 = af(OW2, 36, 18, 1, 1);
    const f16x4 A2_20 = af(OW2, 36, 18, 2, 0), A2_21 = af(OW2, 36, 18, 2, 1);
    const f16x4 A3_00 = af(OW3, 36, 36, 0, 0), A3_01 = af(OW3, 36, 36, 0, 1), A3_02 = af(OW3, 36, 36, 0, 2);
    const f16x4 A3_10 = af(OW3, 36, 36, 1, 0), A3_11 = af(OW3, 36, 36, 1, 1), A3_12 = af(OW3, 36, 36, 1, 2);
    const f16x4 A3_20 = af(OW3, 36, 36, 2, 0), A3_21 = af(OW3, 36, 36, 2, 1), A3_22 = af(OW3, 36, 36, 2, 2);

    const f32x4 C1_0 = bv(OB1, 18, 0), C1_1 = bv(OB1, 18, 1);
    const f32x4 C2_0 = bv(OB2, 36, 0), C2_1 = bv(OB2, 36, 1), C2_2 = bv(OB2, 36, 2);
    const f32x4 C3_0 = bv(OB3, 36, 0), C3_1 = bv(OB3, 36, 1), C3_2 = bv(OB3, 36, 2);
    const f32x4 V4_0 = bv(OW4, 36, 0), V4_1 = bv(OW4, 36, 1), V4_2 = bv(OW4, 36, 2);
    const float b4s  = sw[OB4];

    const int gw = (blockIdx.x * blockDim.x + t) >> 6;
    const int nw = (gridDim.x * blockDim.x) >> 6;

    // ---- prefetch-rotate state for pair p (identical to R1) ----
    float cxa0, cxa1, cxa2, cxa3, cxb0, cxb1, cxb2, cxb3;
    int cca = 0, ccb = 0;
    if (gw < NPAIRS) {
        const int kb = gw * 32;
        cxa0 = x[0 * KN + kb + n];      cxb0 = x[0 * KN + kb + 16 + n];
        cxa1 = x[1 * KN + kb + n];      cxb1 = x[1 * KN + kb + 16 + n];
        cxa2 = x[2 * KN + kb + n];      cxb2 = x[2 * KN + kb + 16 + n];
        cxa3 = x[3 * KN + kb + n];      cxb3 = x[3 * KN + kb + 16 + n];
        cca  = tidx[2 * (kb + n) + 1];  ccb  = tidx[2 * (kb + 16 + n) + 1];
    }

    auto rl = [](f32x4 v) {            // relu + f32->f16, layout-preserving
        f16x4 h;
#pragma unroll
        for (int r = 0; r < 4; ++r) h[r] = (_Float16)fmaxf(v[r], 0.0f);
        return h;
    };

    for (int p = gw; p < NPAIRS; ) {
        const int pn = p + nw;
        const float xa0 = cxa0, xa1 = cxa1, xa2 = cxa2, xa3 = cxa3;
        const float xb0 = cxb0, xb1 = cxb1, xb2 = cxb2, xb3 = cxb3;
        const int cola = cca, colb = ccb;
        if (pn < NPAIRS) {
            const int kb = pn * 32;
            cxa0 = x[0 * KN + kb + n];      cxb0 = x[0 * KN + kb + 16 + n];
            cxa1 = x[1 * KN + kb + n];      cxb1 = x[1 * KN + kb + 16 + n];
            cxa2 = x[2 * KN + kb + n];      cxb2 = x[2 * KN + kb + 16 + n];
            cxa3 = x[3 * KN + kb + n];      cxb3 = x[3 * KN + kb + 16 + n];
            cca  = tidx[2 * (kb + n) + 1];  ccb  = tidx[2 * (kb + 16 + n) + 1];
        }

        // ---- B0 = x^T fragment: k=quad*4+j = channel (real k<4 -> quad 0) ----
        f16x4 B0a = {}, B0b = {};
        if (quad == 0) {
            B0a[0] = (_Float16)xa0; B0a[1] = (_Float16)xa1;
            B0a[2] = (_Float16)xa2; B0a[3] = (_Float16)xa3;
            B0b[0] = (_Float16)xb0; B0b[1] = (_Float16)xb1;
            B0b[2] = (_Float16)xb2; B0b[3] = (_Float16)xb3;
        }

        // ---- L1: D1[feat][elem], 2 feat-tiles ----
        f32x4 d1a0 = MFMA16(A1_0, B0a, C1_0);
        f32x4 d1b0 = MFMA16(A1_0, B0b, C1_0);
        f32x4 d1a1 = MFMA16(A1_1, B0a, C1_1);
        f32x4 d1b1 = MFMA16(A1_1, B0b, C1_1);
        const f16x4 B1a0 = rl(d1a0), B1a1 = rl(d1a1);
        const f16x4 B1b0 = rl(d1b0), B1b1 = rl(d1b1);

        // ---- L2: 3 feat-tiles x 2 k-slices ----
        f32x4 d2a0 = MFMA16(A2_00, B1a0, C2_0);  d2a0 = MFMA16(A2_01, B1a1, d2a0);
        f32x4 d2b0 = MFMA16(A2_00, B1b0, C2_0);  d2b0 = MFMA16(A2_01, B1b1, d2b0);
        f32x4 d2a1 = MFMA16(A2_10, B1a0, C2_1);  d2a1 = MFMA16(A2_11, B1a1, d2a1);
        f32x4 d2b1 = MFMA16(A2_10, B1b0, C2_1);  d2b1 = MFMA16(A2_11, B1b1, d2b1);
        f32x4 d2a2 = MFMA16(A2_20, B1a0, C2_2);  d2a2 = MFMA16(A2_21, B1a1, d2a2);
        f32x4 d2b2 = MFMA16(A2_20, B1b0, C2_2);  d2b2 = MFMA16(A2_21, B1b1, d2b2);
        const f16x4 B2a0 = rl(d2a0), B2a1 = rl(d2a1), B2a2 = rl(d2a2);
        const f16x4 B2b0 = rl(d2b0), B2b1 = rl(d2b1), B2b2 = rl(d2b2);

        // ---- L3: 3 feat-tiles x 3 k-slices ----
        f32x4 d3a0 = MFMA16(A3_00, B2a0, C3_0);
        d3a0 = MFMA16(A3_01, B2a1, d3a0);  d3a0 = MFMA16(A3_02, B2a2, d3a0);
        f32x4 d3b0 = MFMA16(A3_00, B2b0, C3_0);
        d3b0 = MFMA16(A3_01, B2b1, d3b0);  d3b0 = MFMA16(A3_02, B2b2, d3b0);
        f32x4 d3a1 = MFMA16(A3_10, B2a0, C3_1);
        d3a1 = MFMA16(A3_11, B2a1, d3a1);  d3a1 = MFMA16(A3_12, B2a2, d3a1);
        f32x4 d3b1 = MFMA16(A3_10, B2b0, C3_1);
        d3b1 = MFMA16(A3_11, B2b1, d3b1);  d3b1 = MFMA16(A3_12, B2b2, d3b1);
        f32x4 d3a2 = MFMA16(A3_20, B2a0, C3_2);
        d3a2 = MFMA16(A3_21, B2a1, d3a2);  d3a2 = MFMA16(A3_22, B2a2, d3a2);
        f32x4 d3b2 = MFMA16(A3_20, B2b0, C3_2);
        d3b2 = MFMA16(A3_21, B2b1, d3b2);  d3b2 = MFMA16(A3_22, B2b2, d3b2);

        // ---- L4: per-lane partial over its 12 feats, reduce across quads ----
        float pa = 0.0f, pb = 0.0f;
#pragma unroll
        for (int r = 0; r < 4; ++r) {
            pa = fmaf(V4_0[r], fmaxf(d3a0[r], 0.0f), pa);
            pa = fmaf(V4_1[r], fmaxf(d3a1[r], 0.0f), pa);
            pa = fmaf(V4_2[r], fmaxf(d3a2[r], 0.0f), pa);
            pb = fmaf(V4_0[r], fmaxf(d3b0[r], 0.0f), pb);
            pb = fmaf(V4_1[r], fmaxf(d3b1[r], 0.0f), pb);
            pb = fmaf(V4_2[r], fmaxf(d3b2[r], 0.0f), pb);
        }
        pa += __shfl_xor(pa, 16);  pa += __shfl_xor(pa, 32);
        pb += __shfl_xor(pb, 16);  pb += __shfl_xor(pb, 32);

        if (quad == 0)      atomicMax(&outU[cola], encodeF(pa + b4s) - ENC_SENT);
        else if (quad == 1) atomicMax(&outU[colb], encodeF(pb + b4s) - ENC_SENT);

        p = pn;
    }
}

__global__ __launch_bounds__(256) void init_kernel(unsigned* __restrict__ outU) {
    int gid = blockIdx.x * blockDim.x + threadIdx.x;
    if (gid < NCOLS) outU[gid] = 0u;   // == encode(SENTINEL) - bias
}

__global__ __launch_bounds__(256) void decode_kernel(unsigned* __restrict__ outU,
                                                     int out_size) {
    int gid = blockIdx.x * blockDim.x + threadIdx.x;
    if (gid < out_size) {
        float r = (gid < NCOLS) ? decodeF(outU[gid] + ENC_SENT) : 1.0f;
        ((float*)outU)[gid] = r;
    }
}

extern "C" void kernel_launch(void* const* d_in, const int* in_sizes, int n_in,
                              void* d_out, int out_size, void* d_ws, size_t ws_size,
                              hipStream_t stream) {
    const float* x    = (const float*)d_in[0];   // (1,4,1,K)
    const int*   tidx = (const int*)d_in[1];     // (K,2)
    const float* W1 = (const float*)d_in[2];
    const float* b1 = (const float*)d_in[3];
    const float* W2 = (const float*)d_in[4];
    const float* b2 = (const float*)d_in[5];
    const float* W3 = (const float*)d_in[6];
    const float* b3 = (const float*)d_in[7];
    const float* W4 = (const float*)d_in[8];
    const float* b4 = (const float*)d_in[9];
    unsigned* outU = (unsigned*)d_out;

    init_kernel<<<(NCOLS + 255) / 256, 256, 0, stream>>>(outU);

    mlp_scatter_mfma<<<NBLK, NTHR, 0, stream>>>(
        x, tidx, W1, b1, W2, b2, W3, b3, W4, b4, outU);

    decode_kernel<<<(out_size + 255) / 256, 256, 0, stream>>>(outU, out_size);
}